// Round 13
// baseline (118.991 us; speedup 1.0000x reference)
//
#include <hip/hip_runtime.h>

#define N_ 64
#define C_ 4
#define D_ 2048
#define K_ 64
#define O_ 256
#define L_ 1985
#define XCOPY 2116         // stride of shifted bf16 copies (shorts)
#define SPITCH 2012        // bf16 staging pitch (shorts): >=2000, bank-spread
#define NTILE 125          // ceil(L_/16)

typedef __attribute__((ext_vector_type(8))) short s16x8;
typedef __attribute__((ext_vector_type(4))) float f32x4;

// lgkmcnt-only barrier: global stores stay in flight across it
#define BAR_LGKM() do { \
    asm volatile("s_waitcnt lgkmcnt(0)\n\ts_barrier" ::: "memory"); \
    __builtin_amdgcn_sched_barrier(0); \
} while (0)

__device__ __forceinline__ unsigned short f2bf(float f) {
    union { float f; unsigned u; } v; v.f = f;
    unsigned u = v.u;
    u += 0x7fffu + ((u >> 16) & 1u);   // RNE
    return (unsigned short)(u >> 16);
}

__device__ __forceinline__ float bf2f(unsigned short b) {
    union { unsigned u; float f; } v;
    v.u = (unsigned)b << 16;
    return v.f;
}

// weight (O,C,K) fp32 -> bf16, plus yn/64 (pre-scaled norm)
__global__ __launch_bounds__(256) void prep_w(const float* __restrict__ w,
                                              unsigned short* __restrict__ wb,
                                              float* __restrict__ ynK) {
    int o = blockIdx.x;
    int tid = threadIdx.x;
    int c = tid >> 6, k = tid & 63;
    size_t idx = (size_t)(o * C_ + c) * K_ + k;
    float v = w[idx];
    wb[idx] = f2bf(v);
    float s = v * v;
    for (int off = 32; off > 0; off >>= 1) s += __shfl_down(s, off, 64);
    if (k == 0) ynK[o * C_ + c] = s * 0.015625f;
}

// One block per (n,c), 16 waves, bf16 double-buffered staging, ONE barrier per
// stage. NEW: wave-parity phase stagger — odd waves drain-then-compute, even
// waves compute-then-drain, so ~half the waves issue stores at any instant
// (time-uniform store issue instead of per-stage compute/drain bursts).
__global__ __launch_bounds__(1024) void shapelet_main(const float* __restrict__ x,
                                                      const unsigned short* __restrict__ wb,
                                                      const float* __restrict__ ynK,
                                                      float* __restrict__ out) {
    __shared__ __align__(16) unsigned short xs[4][XCOPY]; // xs[s][i] = bf16(x[i+s])
    __shared__ float xn[D_];                              // window sumsq / 64
    __shared__ __align__(16) unsigned short stg[2][16 * SPITCH]; // bf16 staging x2

    int nc = blockIdx.x;
    int c = nc & (C_ - 1);
    const float* xrow = x + (size_t)nc * D_;
    int tid = threadIdx.x;

    float* z    = (float*)stg;          // [0..2111]  x^2, zero-padded
    float* pre  = (float*)stg + 2176;   // in-block prefix sums
    float* S16v = (float*)stg + 4288;   // 16-elem block sums

    // prologue: bf16 copies + squares straight from global (row is L2-hot)
    for (int i = tid; i < 2112; i += 1024) {
        float v = (i < D_) ? xrow[i] : 0.f;
        z[i] = v * v;
        unsigned short b = f2bf(v);
        #pragma unroll
        for (int s = 0; s < 4; ++s) { int j = i - s; if (j >= 0) xs[s][j] = b; }
    }
    __syncthreads();
    if (tid < 132) {
        float run = 0.f;
        int base = tid * 16;
        #pragma unroll
        for (int j = 0; j < 16; ++j) { pre[base + j] = run; run += z[base + j]; }
        S16v[tid] = run;
    }
    __syncthreads();
    for (int l = tid; l < D_; l += 1024) {
        int a = l >> 4, b = l & 15;
        float s = S16v[a] - pre[a * 16 + b] + S16v[a + 1] + S16v[a + 2]
                + S16v[a + 3] + pre[(a + 4) * 16 + b];
        xn[l] = s * 0.015625f;
    }
    __syncthreads();

    int wave = tid >> 6, lane = tid & 63, lr = lane & 15, hi = lane >> 4;
    const unsigned short* xbase = &xs[lr & 3][(lr & ~3) + hi * 8];
    int dj = lane;

    auto compute_band = [&](int st, int p) {
        int o = st * 16 + lr;
        const s16x8* wp = reinterpret_cast<const s16x8*>(
            wb + ((size_t)o * C_ + c) * K_ + hi * 8);
        s16x8 w0 = wp[0];          // k 0..31
        s16x8 w1 = wp[4];          // k 32..63
        float ynKv = ynK[o * C_ + c];
        #pragma unroll
        for (int i = 0; i < 8; ++i) {
            int t = wave + i * 16;
            int tc = t > 124 ? 124 : t;          // clamp: reads stay in-bounds
            int l0t = tc * 16;
            union { unsigned long long u[2]; s16x8 v; } a0, a1;
            const unsigned long long* p0 = (const unsigned long long*)(xbase + l0t);
            a0.u[0] = p0[0]; a0.u[1] = p0[1];
            const unsigned long long* p1 = (const unsigned long long*)(xbase + l0t + 32);
            a1.u[0] = p1[0]; a1.u[1] = p1[1];
            f32x4 acc = {0.f, 0.f, 0.f, 0.f};
            acc = __builtin_amdgcn_mfma_f32_16x16x32_bf16(a0.v, w0, acc, 0, 0, 0);
            acc = __builtin_amdgcn_mfma_f32_16x16x32_bf16(a1.v, w1, acc, 0, 0, 0);
            f32x4 xv = *reinterpret_cast<const f32x4*>(&xn[l0t + hi * 4]);
            float r0 = fmaxf(fmaf(acc[0], -0.03125f, xv[0] + ynKv), 0.f);
            float r1 = fmaxf(fmaf(acc[1], -0.03125f, xv[1] + ynKv), 0.f);
            float r2 = fmaxf(fmaf(acc[2], -0.03125f, xv[2] + ynKv), 0.f);
            float r3 = fmaxf(fmaf(acc[3], -0.03125f, xv[3] + ynKv), 0.f);
            unsigned long long pk =
                  (unsigned long long)f2bf(r0)
                | ((unsigned long long)f2bf(r1) << 16)
                | ((unsigned long long)f2bf(r2) << 32)
                | ((unsigned long long)f2bf(r3) << 48);
            if (t < NTILE)
                *(unsigned long long*)&stg[p][lr * SPITCH + l0t + hi * 4] = pk;
        }
    };

    auto drain_band = [&](int b, int pb) {
        float* gb = out + ((size_t)nc * O_ + b * 16 + wave) * L_;
        const unsigned short* src = &stg[pb][wave * SPITCH];
        #pragma unroll
        for (int q = 0; q < 8; ++q) {
            int pos = dj * 4 + q * 256;
            if (pos + 4 <= L_) {
                unsigned long long dv = *(const unsigned long long*)(src + pos);
                f32x4 v;
                v[0] = bf2f((unsigned short)(dv));
                v[1] = bf2f((unsigned short)(dv >> 16));
                v[2] = bf2f((unsigned short)(dv >> 32));
                v[3] = bf2f((unsigned short)(dv >> 48));
                __builtin_memcpy(gb + pos, &v, 16);   // dwordx4
            }
        }
        if (dj == 0) gb[L_ - 1] = bf2f(src[L_ - 1]);
    };

    bool drain_first = (wave & 1);
    for (int st = 0; st < 16; ++st) {
        int p = st & 1;
        if (drain_first && st > 0) drain_band(st - 1, p ^ 1);
        compute_band(st, p);
        if (!drain_first && st > 0) drain_band(st - 1, p ^ 1);
        BAR_LGKM();   // stg[p] complete AND stg[p^1] reads done
    }
    drain_band(15, 1);
}

extern "C" void kernel_launch(void* const* d_in, const int* in_sizes, int n_in,
                              void* d_out, int out_size, void* d_ws, size_t ws_size,
                              hipStream_t stream) {
    const float* x = (const float*)d_in[0];
    const float* w = (const float*)d_in[1];
    float* out = (float*)d_out;

    unsigned short* wb = (unsigned short*)d_ws;                     // 128 KiB
    float* ynK = (float*)((char*)d_ws + (size_t)O_ * C_ * K_ * 2);  // 4 KiB

    prep_w<<<O_, 256, 0, stream>>>(w, wb, ynK);
    shapelet_main<<<N_ * C_, 1024, 0, stream>>>(x, wb, ynK, out);
}

// Round 14
// 115.965 us; speedup vs baseline: 1.0261x; 1.0261x over previous
//
#include <hip/hip_runtime.h>

#define N_ 64
#define C_ 4
#define D_ 2048
#define K_ 64
#define O_ 256
#define L_ 1985
#define XSW 2056           // shifted-copy width (covers max frag read 2055)
#define SPITCH 2008        // bf16 staging pitch: >=2000, 16B-aligned rows, 2-way banks
#define NTILE 125          // ceil(L_/16)

typedef __attribute__((ext_vector_type(8))) short s16x8;
typedef __attribute__((ext_vector_type(4))) float f32x4;

// lgkmcnt-only barrier: global stores stay in flight across it
#define BAR_LGKM() do { \
    asm volatile("s_waitcnt lgkmcnt(0)\n\ts_barrier" ::: "memory"); \
    __builtin_amdgcn_sched_barrier(0); \
} while (0)

__device__ __forceinline__ unsigned short f2bf(float f) {
    union { float f; unsigned u; } v; v.f = f;
    unsigned u = v.u;
    u += 0x7fffu + ((u >> 16) & 1u);   // RNE
    return (unsigned short)(u >> 16);
}
__device__ __forceinline__ float bflo(unsigned u) {
    union { unsigned x; float f; } v; v.x = u << 16; return v.f;
}
__device__ __forceinline__ float bfhi(unsigned u) {
    union { unsigned x; float f; } v; v.x = u & 0xffff0000u; return v.f;
}

// weight (O,C,K) fp32 -> bf16, plus yn/64 (pre-scaled norm)
__global__ __launch_bounds__(256) void prep_w(const float* __restrict__ w,
                                              unsigned short* __restrict__ wb,
                                              float* __restrict__ ynK) {
    int o = blockIdx.x;
    int tid = threadIdx.x;
    int c = tid >> 6, k = tid & 63;
    size_t idx = (size_t)(o * C_ + c) * K_ + k;
    float v = w[idx];
    wb[idx] = f2bf(v);
    float s = v * v;
    for (int off = 32; off > 0; off >>= 1) s += __shfl_down(s, off, 64);
    if (k == 0) ynK[o * C_ + c] = s * 0.015625f;
}

// One block per (n,c), 16 waves, bf16 double-buffered staging, 1 barrier/stage
// (R12 skeleton). NEW: LDS instruction diet — 8 shifted copies give b128
// fragment reads; xn lives in 32 VGPRs (stage-invariant); 16B-aligned staging
// gives b128 drain reads. ~28 LDS instr/wave/stage vs 56.
__global__ __launch_bounds__(1024) void shapelet_main(const float* __restrict__ x,
                                                      const unsigned short* __restrict__ wb,
                                                      const float* __restrict__ ynK,
                                                      float* __restrict__ out) {
    __shared__ __align__(16) unsigned short xs8[8][XSW];         // xs8[s][i] = bf16(x[i+s])
    __shared__ __align__(16) unsigned short stg[2][16 * SPITCH]; // bf16 staging x2

    int nc = blockIdx.x;
    int c = nc & (C_ - 1);
    const float* xrow = x + (size_t)nc * D_;
    int tid = threadIdx.x;

    // prologue scratch overlaid on stg (consumed before stage 0)
    float* xf   = (float*)stg;          // [0..2112)   x values, zero-padded
    float* z    = (float*)stg + 2112;   // [0..2112)   squares
    float* pre  = (float*)stg + 4288;   // [0..2112)   in-block prefix sums
    float* S16v = (float*)stg + 6400;   // [0..132)
    float* xnl  = (float*)stg + 6592;   // [0..2000)   window sumsq / 64

    for (int i = tid; i < 2112; i += 1024) {
        float v = (i < D_) ? xrow[i] : 0.f;
        xf[i] = v;
        z[i] = v * v;
    }
    __syncthreads();
    for (int j = tid; j < XSW; j += 1024) {
        #pragma unroll
        for (int s = 0; s < 8; ++s) xs8[s][j] = f2bf(xf[j + s]);
    }
    if (tid < 132) {
        float run = 0.f;
        int base = tid * 16;
        #pragma unroll
        for (int j = 0; j < 16; ++j) { pre[base + j] = run; run += z[base + j]; }
        S16v[tid] = run;
    }
    __syncthreads();
    for (int l = tid; l < 2000; l += 1024) {
        int a = l >> 4, b = l & 15;
        float s = S16v[a] - pre[a * 16 + b] + S16v[a + 1] + S16v[a + 2]
                + S16v[a + 3] + pre[(a + 4) * 16 + b];
        xnl[l] = s * 0.015625f;
    }
    __syncthreads();

    int wave = tid >> 6, lane = tid & 63, lr = lane & 15, hi = lane >> 4;
    const unsigned short* xsc = xs8[lr & 7];     // this lane's shifted copy
    int dj = lane;

    // hoist stage-invariant window norms into registers (8 x f32x4)
    f32x4 xnr[8];
    #pragma unroll
    for (int i = 0; i < 8; ++i) {
        int t = wave + i * 16;
        int tc = t > 124 ? 124 : t;
        xnr[i] = *reinterpret_cast<const f32x4*>(&xnl[tc * 16 + hi * 4]);
    }
    __syncthreads();   // xnl scratch free; stg usable

    auto drain_band = [&](int b, int pb) {
        float* gb = out + ((size_t)nc * O_ + b * 16 + wave) * L_;
        const unsigned short* src = &stg[pb][wave * SPITCH];
        #pragma unroll
        for (int q = 0; q < 4; ++q) {
            int pos = dj * 8 + q * 512;
            if (pos + 8 <= L_) {
                s16x8 dv = *reinterpret_cast<const s16x8*>(src + pos);  // ds_read_b128
                const unsigned* du = (const unsigned*)&dv;
                f32x4 v0, v1;
                v0[0] = bflo(du[0]); v0[1] = bfhi(du[0]);
                v0[2] = bflo(du[1]); v0[3] = bfhi(du[1]);
                v1[0] = bflo(du[2]); v1[1] = bfhi(du[2]);
                v1[2] = bflo(du[3]); v1[3] = bfhi(du[3]);
                __builtin_memcpy(gb + pos, &v0, 16);        // dwordx4
                __builtin_memcpy(gb + pos + 4, &v1, 16);    // dwordx4
            }
        }
        if (dj == 0) {
            union { unsigned x; float f; } v; v.x = (unsigned)src[L_ - 1] << 16;
            gb[L_ - 1] = v.f;
        }
    };

    for (int st = 0; st < 16; ++st) {
        int p = st & 1;
        // ---- compute band st into stg[p] ----
        int o = st * 16 + lr;
        const s16x8* wp = reinterpret_cast<const s16x8*>(
            wb + ((size_t)o * C_ + c) * K_ + hi * 8);
        s16x8 w0 = wp[0];          // k 0..31
        s16x8 w1 = wp[4];          // k 32..63
        float ynKv = ynK[o * C_ + c];

        #pragma unroll
        for (int i = 0; i < 8; ++i) {
            int t = wave + i * 16;
            int tc = t > 124 ? 124 : t;
            int l0t = tc * 16;
            int ja = l0t + (lr & ~7) + hi * 8;   // 8-short aligned in this copy
            s16x8 a0 = *reinterpret_cast<const s16x8*>(&xsc[ja]);        // b128
            s16x8 a1 = *reinterpret_cast<const s16x8*>(&xsc[ja + 32]);   // b128
            f32x4 acc = {0.f, 0.f, 0.f, 0.f};
            acc = __builtin_amdgcn_mfma_f32_16x16x32_bf16(a0, w0, acc, 0, 0, 0);
            acc = __builtin_amdgcn_mfma_f32_16x16x32_bf16(a1, w1, acc, 0, 0, 0);
            f32x4 xv = xnr[i];
            float r0 = fmaxf(fmaf(acc[0], -0.03125f, xv[0] + ynKv), 0.f);
            float r1 = fmaxf(fmaf(acc[1], -0.03125f, xv[1] + ynKv), 0.f);
            float r2 = fmaxf(fmaf(acc[2], -0.03125f, xv[2] + ynKv), 0.f);
            float r3 = fmaxf(fmaf(acc[3], -0.03125f, xv[3] + ynKv), 0.f);
            unsigned long long pk =
                  (unsigned long long)f2bf(r0)
                | ((unsigned long long)f2bf(r1) << 16)
                | ((unsigned long long)f2bf(r2) << 32)
                | ((unsigned long long)f2bf(r3) << 48);
            if (t < NTILE)
                *(unsigned long long*)&stg[p][lr * SPITCH + l0t + hi * 4] = pk;  // b64
        }

        // ---- then drain band st-1 from stg[p^1] (stores fire-and-forget) ----
        if (st > 0) drain_band(st - 1, p ^ 1);
        BAR_LGKM();   // stg[p] complete AND stg[p^1] reads done
    }
    drain_band(15, 1);
}

extern "C" void kernel_launch(void* const* d_in, const int* in_sizes, int n_in,
                              void* d_out, int out_size, void* d_ws, size_t ws_size,
                              hipStream_t stream) {
    const float* x = (const float*)d_in[0];
    const float* w = (const float*)d_in[1];
    float* out = (float*)d_out;

    unsigned short* wb = (unsigned short*)d_ws;                     // 128 KiB
    float* ynK = (float*)((char*)d_ws + (size_t)O_ * C_ * K_ * 2);  // 4 KiB

    prep_w<<<O_, 256, 0, stream>>>(w, wb, ynK);
    shapelet_main<<<N_ * C_, 1024, 0, stream>>>(x, wb, ynK, out);
}

// Round 15
// 112.252 us; speedup vs baseline: 1.0600x; 1.0331x over previous
//
#include <hip/hip_runtime.h>

#define N_ 64
#define C_ 4
#define D_ 2048
#define K_ 64
#define O_ 256
#define L_ 1985
#define XSW4 2064          // shifted-copy width (shorts), 16B-aligned rows
#define SPITCH 2008        // bf16 staging pitch (shorts): 16B-aligned rows
#define NTILE 125          // ceil(L_/16)
#define CW 12              // compute waves
#define NIT 11             // ceil(125/12)

typedef __attribute__((ext_vector_type(8))) short s16x8;
typedef __attribute__((ext_vector_type(4))) float f32x4;

// lgkmcnt-only barrier: global stores stay in flight across it
#define BAR_LGKM() do { \
    asm volatile("s_waitcnt lgkmcnt(0)\n\ts_barrier" ::: "memory"); \
    __builtin_amdgcn_sched_barrier(0); \
} while (0)

__device__ __forceinline__ unsigned short f2bf(float f) {
    union { float f; unsigned u; } v; v.f = f;
    unsigned u = v.u;
    u += 0x7fffu + ((u >> 16) & 1u);   // RNE
    return (unsigned short)(u >> 16);
}
__device__ __forceinline__ float bflo(unsigned u) {
    union { unsigned x; float f; } v; v.x = u << 16; return v.f;
}
__device__ __forceinline__ float bfhi(unsigned u) {
    union { unsigned x; float f; } v; v.x = u & 0xffff0000u; return v.f;
}

// weight (O,C,K) fp32 -> bf16, plus yn/64 (pre-scaled norm)
__global__ __launch_bounds__(256) void prep_w(const float* __restrict__ w,
                                              unsigned short* __restrict__ wb,
                                              float* __restrict__ ynK) {
    int o = blockIdx.x;
    int tid = threadIdx.x;
    int c = tid >> 6, k = tid & 63;
    size_t idx = (size_t)(o * C_ + c) * K_ + k;
    float v = w[idx];
    wb[idx] = f2bf(v);
    float s = v * v;
    for (int off = 32; off > 0; off >>= 1) s += __shfl_down(s, off, 64);
    if (k == 0) ynK[o * C_ + c] = s * 0.015625f;
}

// One block per (n,c), 16 waves, bf16 double-buffered staging, 1 barrier/stage.
// PRODUCER/CONSUMER SPLIT: waves 0-11 compute band st into stg[p]; waves 12-15
// are dedicated writers streaming band st-1 from stg[p^1] to HBM. Store issue
// is continuous from the barrier instant, decoupled from MFMA dependencies.
__global__ __launch_bounds__(1024) void shapelet_main(const float* __restrict__ x,
                                                      const unsigned short* __restrict__ wb,
                                                      const float* __restrict__ ynK,
                                                      float* __restrict__ out) {
    __shared__ __align__(16) unsigned short xs4[4][XSW4];        // xs4[s][i] = bf16(x[i+s])
    __shared__ float xnl[2000];                                  // window sumsq / 64
    __shared__ __align__(16) unsigned short stg[2][16 * SPITCH]; // bf16 staging x2

    int nc = blockIdx.x;
    int c = nc & (C_ - 1);
    const float* xrow = x + (size_t)nc * D_;
    int tid = threadIdx.x;

    // prologue scratch overlaid on stg (consumed before stage 0)
    float* xf   = (float*)stg;          // [0..2112)  x values, zero-padded
    float* z    = (float*)stg + 2112;   // [0..2112)  squares
    float* pre  = (float*)stg + 4288;   // [0..2112)  in-block prefix sums
    float* S16v = (float*)stg + 6400;   // [0..132)

    for (int i = tid; i < 2112; i += 1024) {
        float v = (i < D_) ? xrow[i] : 0.f;
        xf[i] = v;
        z[i] = v * v;
    }
    __syncthreads();
    for (int j = tid; j < XSW4; j += 1024) {
        #pragma unroll
        for (int s = 0; s < 4; ++s) xs4[s][j] = f2bf(xf[j + s]);
    }
    if (tid < 132) {
        float run = 0.f;
        int base = tid * 16;
        #pragma unroll
        for (int j = 0; j < 16; ++j) { pre[base + j] = run; run += z[base + j]; }
        S16v[tid] = run;
    }
    __syncthreads();
    for (int l = tid; l < 2000; l += 1024) {
        int a = l >> 4, b = l & 15;
        float s = S16v[a] - pre[a * 16 + b] + S16v[a + 1] + S16v[a + 2]
                + S16v[a + 3] + pre[(a + 4) * 16 + b];
        xnl[l] = s * 0.015625f;
    }
    __syncthreads();   // prologue scratch dead; stg usable

    int wave = tid >> 6, lane = tid & 63, lr = lane & 15, hi = lane >> 4;
    const unsigned short* xbase = &xs4[lr & 3][(lr & ~3) + hi * 8];
    bool is_writer = (wave >= CW);
    int wv = wave - CW;

    auto compute_band = [&](int st, int p) {
        int o = st * 16 + lr;
        const s16x8* wp = reinterpret_cast<const s16x8*>(
            wb + ((size_t)o * C_ + c) * K_ + hi * 8);
        s16x8 w0 = wp[0];          // k 0..31
        s16x8 w1 = wp[4];          // k 32..63
        float ynKv = ynK[o * C_ + c];
        #pragma unroll
        for (int i = 0; i < NIT; ++i) {
            int t = wave + i * CW;
            int tc = t > 124 ? 124 : t;          // clamp: reads stay in-bounds
            int l0t = tc * 16;
            union { unsigned long long u[2]; s16x8 v; } a0, a1;
            const unsigned long long* p0 = (const unsigned long long*)(xbase + l0t);
            a0.u[0] = p0[0]; a0.u[1] = p0[1];
            const unsigned long long* p1 = (const unsigned long long*)(xbase + l0t + 32);
            a1.u[0] = p1[0]; a1.u[1] = p1[1];
            f32x4 acc = {0.f, 0.f, 0.f, 0.f};
            acc = __builtin_amdgcn_mfma_f32_16x16x32_bf16(a0.v, w0, acc, 0, 0, 0);
            acc = __builtin_amdgcn_mfma_f32_16x16x32_bf16(a1.v, w1, acc, 0, 0, 0);
            f32x4 xv = *reinterpret_cast<const f32x4*>(&xnl[l0t + hi * 4]);
            float r0 = fmaxf(fmaf(acc[0], -0.03125f, xv[0] + ynKv), 0.f);
            float r1 = fmaxf(fmaf(acc[1], -0.03125f, xv[1] + ynKv), 0.f);
            float r2 = fmaxf(fmaf(acc[2], -0.03125f, xv[2] + ynKv), 0.f);
            float r3 = fmaxf(fmaf(acc[3], -0.03125f, xv[3] + ynKv), 0.f);
            unsigned long long pk =
                  (unsigned long long)f2bf(r0)
                | ((unsigned long long)f2bf(r1) << 16)
                | ((unsigned long long)f2bf(r2) << 32)
                | ((unsigned long long)f2bf(r3) << 48);
            if (t < NTILE)
                *(unsigned long long*)&stg[p][lr * SPITCH + l0t + hi * 4] = pk;  // b64
        }
    };

    auto drain_band = [&](int b, int pb) {
        #pragma unroll
        for (int rr = 0; rr < 4; ++rr) {
            int r = wv * 4 + rr;
            float* gb = out + ((size_t)nc * O_ + b * 16 + r) * L_;
            const unsigned short* src = &stg[pb][r * SPITCH];
            #pragma unroll
            for (int q = 0; q < 4; ++q) {
                int pos = lane * 8 + q * 512;
                if (pos + 8 <= L_) {
                    s16x8 dv = *reinterpret_cast<const s16x8*>(src + pos);  // b128
                    const unsigned* du = (const unsigned*)&dv;
                    f32x4 v0, v1;
                    v0[0] = bflo(du[0]); v0[1] = bfhi(du[0]);
                    v0[2] = bflo(du[1]); v0[3] = bfhi(du[1]);
                    v1[0] = bflo(du[2]); v1[1] = bfhi(du[2]);
                    v1[2] = bflo(du[3]); v1[3] = bfhi(du[3]);
                    __builtin_memcpy(gb + pos, &v0, 16);        // dwordx4
                    __builtin_memcpy(gb + pos + 4, &v1, 16);    // dwordx4
                }
            }
            if (lane == 0) {
                union { unsigned x; float f; } v; v.x = (unsigned)src[L_ - 1] << 16;
                gb[L_ - 1] = v.f;
            }
        }
    };

    for (int st = 0; st < 16; ++st) {
        int p = st & 1;
        if (!is_writer) compute_band(st, p);          // producers: band st -> stg[p]
        else if (st > 0) drain_band(st - 1, p ^ 1);   // writers: band st-1 -> HBM
        BAR_LGKM();   // stg[p] complete AND stg[p^1] reads done; stores in flight
    }
    if (is_writer) drain_band(15, 1);                 // final band
}

extern "C" void kernel_launch(void* const* d_in, const int* in_sizes, int n_in,
                              void* d_out, int out_size, void* d_ws, size_t ws_size,
                              hipStream_t stream) {
    const float* x = (const float*)d_in[0];
    const float* w = (const float*)d_in[1];
    float* out = (float*)d_out;

    unsigned short* wb = (unsigned short*)d_ws;                     // 128 KiB
    float* ynK = (float*)((char*)d_ws + (size_t)O_ * C_ * K_ * 2);  // 4 KiB

    prep_w<<<O_, 256, 0, stream>>>(w, wb, ynK);
    shapelet_main<<<N_ * C_, 1024, 0, stream>>>(x, wb, ynK, out);
}